// Round 3
// baseline (376.451 us; speedup 1.0000x reference)
//
#include <hip/hip_runtime.h>

constexpr int Bn  = 524288;
constexpr int Cn  = 42;
constexpr int BC  = Bn * Cn;     // 22020096
constexpr int BC4 = BC / 4;      // 5505024 (multiple of 42)
constexpr int B4  = Bn / 4;      // 131072
constexpr float EPSf = 1e-7f;

constexpr int CSTR = 228;        // per-channel dword stride (57 f4, odd -> granule spread)

typedef float f4 __attribute__((ext_vector_type(4)));

__device__ __forceinline__ float frcp(float x) { return __builtin_amdgcn_rcpf(x); }

// Per-channel weight block (dword offsets within channel, 228 dwords total):
//  dL1:   0..59   rows o*12: [w0..w8, bias, pad, pad]          (5 rows, 3 f4 each)
//  dL2:  60..83   W[4][5] row-major (20) + b[4]                (6 f4)
//  dL3:  84..103  W[4][4] (16) + b[4]                          (5 f4)
//  dL4: 104..119  W[3][4] (12) + b[3] + pad                    (4 f4)
//  fL1: 120..167  rows o*8: w0..w7 (5 rows, 2 f4) ; b at 160..164 ; pad
//  fL2: 168..191  W[4][5] + b[4]                               (6 f4)
//  fL3: 192..211  W[4][4] + b[4]                               (5 f4)
//  fL4: 212..227  W[3][4] + b[3] + pad                         (4 f4)

// generic packed layer: W[OUT][IN] row-major then OUT biases, starting at f4 index vb
template<int IN, int OUT, bool RELU>
__device__ __forceinline__ void layerP(const f4* __restrict__ L, int vb,
                                       const float (&in)[4][8], float (&out)[4][8])
{
    constexpr int NV = (IN * OUT + OUT + 3) / 4;
    f4 Bk[NV];
#pragma unroll
    for (int v = 0; v < NV; ++v) Bk[v] = L[vb + v];
#pragma unroll
    for (int o = 0; o < OUT; ++o) {
        float bs = Bk[(IN * OUT + o) >> 2][(IN * OUT + o) & 3];
        float a0 = bs, a1 = bs, a2 = bs, a3 = bs;
#pragma unroll
        for (int i = 0; i < IN; ++i) {
            float w = Bk[(o * IN + i) >> 2][(o * IN + i) & 3];
            a0 = fmaf(w, in[0][i], a0);
            a1 = fmaf(w, in[1][i], a1);
            a2 = fmaf(w, in[2][i], a2);
            a3 = fmaf(w, in[3][i], a3);
        }
        out[0][o] = RELU ? fmaxf(a0, 0.f) : a0;
        out[1][o] = RELU ? fmaxf(a1, 0.f) : a1;
        out[2][o] = RELU ? fmaxf(a2, 0.f) : a2;
        out[3][o] = RELU ? fmaxf(a3, 0.f) : a3;
    }
}

__global__ __launch_bounds__(256, 4) void scat_main(
    const float* __restrict__ tau,
    const float* __restrict__ mu_direct,
    const float* __restrict__ mu_diffuse,
    const float* __restrict__ cons,
    const float* __restrict__ dW1, const float* __restrict__ db1,
    const float* __restrict__ dW2, const float* __restrict__ db2,
    const float* __restrict__ dW3, const float* __restrict__ db3,
    const float* __restrict__ dW4, const float* __restrict__ db4,
    const float* __restrict__ fW1, const float* __restrict__ fb1,
    const float* __restrict__ fW2, const float* __restrict__ fb2,
    const float* __restrict__ fW3, const float* __restrict__ fb3,
    const float* __restrict__ fW4, const float* __restrict__ fb4,
    float* __restrict__ out)
{
    __shared__ f4 ldsv[Cn * CSTR / 4];          // 38304 B
    float* lds = reinterpret_cast<float*>(ldsv);

    auto stage = [&](const float* __restrict__ src, int n, int per_c, auto offfn) {
        for (int i = threadIdx.x; i < n; i += 256) {
            int cc  = i / per_c;
            int rem = i - cc * per_c;
            lds[cc * CSTR + offfn(rem)] = src[i];
        }
    };
    // direct net
    stage(dW1, 1890, 45, [](int r) { return (r / 9) * 12 + (r % 9); });
    stage(db1,  210,  5, [](int r) { return r * 12 + 9; });
    stage(dW2,  840, 20, [](int r) { return 60 + r; });
    stage(db2,  168,  4, [](int r) { return 80 + r; });
    stage(dW3,  672, 16, [](int r) { return 84 + r; });
    stage(db3,  168,  4, [](int r) { return 100 + r; });
    stage(dW4,  504, 12, [](int r) { return 104 + r; });
    stage(db4,  126,  3, [](int r) { return 116 + r; });
    // diffuse net
    stage(fW1, 1680, 40, [](int r) { return 120 + (r / 8) * 8 + (r % 8); });
    stage(fb1,  210,  5, [](int r) { return 160 + r; });
    stage(fW2,  840, 20, [](int r) { return 168 + r; });
    stage(fb2,  168,  4, [](int r) { return 188 + r; });
    stage(fW3,  672, 16, [](int r) { return 192 + r; });
    stage(fb3,  168,  4, [](int r) { return 208 + r; });
    stage(fW4,  504, 12, [](int r) { return 212 + r; });
    stage(fb4,  126,  3, [](int r) { return 224 + r; });
    __syncthreads();

    const int p = blockIdx.x * 256 + threadIdx.x;   // < BC4, exact grid
    const int c = p % Cn;
    const int b = p / Cn;
    const f4* L = ldsv + c * (CSTR / 4);            // 57 f4 per channel

    float mud[4], invd[4];
    float xc[4][9];

    // tau reduction + transmittances + input loads (tau stream-once: nt)
#pragma unroll
    for (int q = 0; q < 4; ++q) {
        const int pq = p + q * BC4;
        const f4* t4 = reinterpret_cast<const f4*>(tau) + pq * 2;
        f4 ta = __builtin_nontemporal_load(t4);
        f4 tb = __builtin_nontemporal_load(t4 + 1);
        float tt = ((ta.x + ta.y) + (ta.z + ta.w)) + ((tb.x + tb.y) + (tb.z + tb.w));
        const int bq = b + q * B4;
        float md = mu_direct[bq];
        float mf = mu_diffuse[bq];
        const f4* c4 = reinterpret_cast<const f4*>(cons) + bq * 2;
        f4 ca = c4[0], cb = c4[1];
        xc[q][0] = ca.x; xc[q][1] = ca.y; xc[q][2] = ca.z; xc[q][3] = ca.w;
        xc[q][4] = cb.x; xc[q][5] = cb.y; xc[q][6] = cb.z; xc[q][7] = cb.w;
        float id = frcp(md + EPSf);
        float iff = frcp(mf + EPSf);
        __builtin_nontemporal_store(__expf(-tt * id),  out + pq);
        __builtin_nontemporal_store(__expf(-tt * iff), out + BC + pq);
        mud[q] = md; invd[q] = id;
    }

    float h1[4][8], h2[4][8], h3[4][8], oo[4][8];

    // ---------------- diffuse net (input: raw constituents) ----------------
    {
        f4 fb = L[40];
        float b4v = L[41][0];
#pragma unroll
        for (int o = 0; o < 5; ++o) {
            f4 wa = L[30 + 2 * o], wb = L[31 + 2 * o];
            float bs = (o < 4) ? fb[o] : b4v;
            float a0 = bs, a1 = bs, a2 = bs, a3 = bs;
#pragma unroll
            for (int i = 0; i < 8; ++i) {
                float w = (i < 4) ? wa[i] : wb[i - 4];
                a0 = fmaf(w, xc[0][i], a0);
                a1 = fmaf(w, xc[1][i], a1);
                a2 = fmaf(w, xc[2][i], a2);
                a3 = fmaf(w, xc[3][i], a3);
            }
            h1[0][o] = fmaxf(a0, 0.f);
            h1[1][o] = fmaxf(a1, 0.f);
            h1[2][o] = fmaxf(a2, 0.f);
            h1[3][o] = fmaxf(a3, 0.f);
        }
    }
    layerP<5, 4, true >(L, 42, h1, h2);
    layerP<4, 4, true >(L, 48, h2, h3);
    layerP<4, 3, false>(L, 53, h3, oo);
#pragma unroll
    for (int q = 0; q < 4; ++q) {
        float v0 = oo[q][0], v1 = oo[q][1], v2 = oo[q][2];
        float m = fmaxf(fmaxf(v0, v1), v2);
        float e0 = __expf(v0 - m), e1 = __expf(v1 - m), e2 = __expf(v2 - m);
        float rs = frcp(e0 + e1 + e2);
        int base = 5 * BC + (p + q * BC4) * 3;
        __builtin_nontemporal_store(e0 * rs, out + base + 0);
        __builtin_nontemporal_store(e1 * rs, out + base + 1);
        __builtin_nontemporal_store(e2 * rs, out + base + 2);
    }

    // ---------------- direct net (input: [cons/(mu_d+eps), mu_d]) ----------------
#pragma unroll
    for (int q = 0; q < 4; ++q) {
#pragma unroll
        for (int i = 0; i < 8; ++i) xc[q][i] *= invd[q];
        xc[q][8] = mud[q];
    }
#pragma unroll
    for (int o = 0; o < 5; ++o) {
        f4 wa = L[3 * o], wb = L[3 * o + 1], wcv = L[3 * o + 2];
        float bs = wcv[1];
        float a0 = bs, a1 = bs, a2 = bs, a3 = bs;
#pragma unroll
        for (int i = 0; i < 9; ++i) {
            float w = (i < 4) ? wa[i] : (i < 8) ? wb[i - 4] : wcv[0];
            a0 = fmaf(w, xc[0][i], a0);
            a1 = fmaf(w, xc[1][i], a1);
            a2 = fmaf(w, xc[2][i], a2);
            a3 = fmaf(w, xc[3][i], a3);
        }
        h1[0][o] = fmaxf(a0, 0.f);
        h1[1][o] = fmaxf(a1, 0.f);
        h1[2][o] = fmaxf(a2, 0.f);
        h1[3][o] = fmaxf(a3, 0.f);
    }
    layerP<5, 4, true >(L, 15, h1, h2);
    layerP<4, 4, true >(L, 21, h2, h3);
    layerP<4, 3, false>(L, 26, h3, oo);
#pragma unroll
    for (int q = 0; q < 4; ++q) {
        float v0 = oo[q][0], v1 = oo[q][1], v2 = oo[q][2];
        float m = fmaxf(fmaxf(v0, v1), v2);
        float e0 = __expf(v0 - m), e1 = __expf(v1 - m), e2 = __expf(v2 - m);
        float rs = frcp(e0 + e1 + e2);
        int base = 2 * BC + (p + q * BC4) * 3;
        __builtin_nontemporal_store(e0 * rs, out + base + 0);
        __builtin_nontemporal_store(e1 * rs, out + base + 1);
        __builtin_nontemporal_store(e2 * rs, out + base + 2);
    }
}

extern "C" void kernel_launch(void* const* d_in, const int* in_sizes, int n_in,
                              void* d_out, int out_size, void* d_ws, size_t ws_size,
                              hipStream_t stream) {
    const float* tau  = (const float*)d_in[0];
    const float* mu_d = (const float*)d_in[1];
    const float* mu_f = (const float*)d_in[2];
    const float* cons = (const float*)d_in[3];

    dim3 grid(BC4 / 256);   // 21504 blocks, exact cover of BC/4 threads
    scat_main<<<grid, 256, 0, stream>>>(
        tau, mu_d, mu_f, cons,
        (const float*)d_in[4],  (const float*)d_in[5],
        (const float*)d_in[6],  (const float*)d_in[7],
        (const float*)d_in[8],  (const float*)d_in[9],
        (const float*)d_in[10], (const float*)d_in[11],
        (const float*)d_in[12], (const float*)d_in[13],
        (const float*)d_in[14], (const float*)d_in[15],
        (const float*)d_in[16], (const float*)d_in[17],
        (const float*)d_in[18], (const float*)d_in[19],
        (float*)d_out);
}